// Round 1
// baseline (3501.146 us; speedup 1.0000x reference)
//
#include <hip/hip_runtime.h>

#define NQ 4096
#define NPT 1024

// ---------- K1: f8t[b][n][c] = (w_in @ f + b_in), layout (B, N, 8) ----------
__global__ __launch_bounds__(256) void f8_kernel(const float* __restrict__ f,
                                                 const float* __restrict__ w_in,
                                                 const float* __restrict__ b_in,
                                                 float* __restrict__ f8t) {
  int t = blockIdx.x * 256 + threadIdx.x;      // 0..32767  (b*4096+n)
  int b = t >> 12, n = t & 4095;
  const float* fb = f + (size_t)b * 3 * NQ + n;
  float f0 = fb[0], f1 = fb[NQ], f2 = fb[2 * NQ];
  float out[8];
#pragma unroll
  for (int o = 0; o < 8; o++) {
    out[o] = w_in[o * 3 + 0] * f0 + w_in[o * 3 + 1] * f1 + w_in[o * 3 + 2] * f2 + b_in[o];
  }
  float4* dst = (float4*)(f8t + ((size_t)t << 3));
  dst[0] = make_float4(out[0], out[1], out[2], out[3]);
  dst[1] = make_float4(out[4], out[5], out[6], out[7]);
}

// ---------- K2: kNN (K=16 smallest of d = sqn + sqm - 2*dot, tie -> lower idx) ----------
__global__ __launch_bounds__(128) void knn_kernel(const float* __restrict__ x,
                                                  int* __restrict__ knn) {
#pragma clang fp contract(off)
  __shared__ float4 pts[NQ];   // 64 KB: x,y,z,sq
  int b = blockIdx.x >> 5;
  int n0 = (blockIdx.x & 31) << 7;
  const float* xb = x + (size_t)b * 3 * NQ;
  for (int i = threadIdx.x; i < NQ; i += 128) {
    float px = xb[i], py = xb[NQ + i], pz = xb[2 * NQ + i];
    float sq = (px * px + py * py) + pz * pz;   // ((xx+yy)+zz), no fma
    pts[i] = make_float4(px, py, pz, sq);
  }
  __syncthreads();
  int n = n0 + threadIdx.x;
  float4 q = pts[n];
  float bd[16]; int bi[16];
#pragma unroll
  for (int i = 0; i < 16; i++) { bd[i] = 3.4e38f; bi[i] = 0x40000000; }
  float thr = 3.4e38f;
  for (int m = 0; m < NQ; m++) {
    float4 p = pts[m];
    float dot = (q.x * p.x + q.y * p.y) + q.z * p.z;
    float d = (q.w + p.w) - 2.0f * dot;
    if (d < thr) {
      // evict slot with max d; ties -> max index (top_k keeps lower index)
      int es = 0; float ev = bd[0]; int eb = bi[0];
#pragma unroll
      for (int i = 1; i < 16; i++) {
        bool w = (bd[i] > ev) || ((bd[i] == ev) && (bi[i] > eb));
        if (w) { es = i; ev = bd[i]; eb = bi[i]; }
      }
#pragma unroll
      for (int i = 0; i < 16; i++) if (i == es) { bd[i] = d; bi[i] = m; }
      float t2 = bd[0];
#pragma unroll
      for (int i = 1; i < 16; i++) t2 = fmaxf(t2, bd[i]);
      thr = t2;
    }
  }
  int4* dst = (int4*)(knn + (((size_t)(b << 12) + n) << 4));
  dst[0] = make_int4(bi[0], bi[1], bi[2], bi[3]);
  dst[1] = make_int4(bi[4], bi[5], bi[6], bi[7]);
  dst[2] = make_int4(bi[8], bi[9], bi[10], bi[11]);
  dst[3] = make_int4(bi[12], bi[13], bi[14], bi[15]);
}

// ---------- K3: FPS, bitwise-matching numpy fp32 path ----------
__global__ __launch_bounds__(256) void fps_kernel(const float* __restrict__ x,
                                                  int* __restrict__ fps) {
#pragma clang fp contract(off)
  int b = blockIdx.x;
  int t = threadIdx.x;
  const float* xb = x + (size_t)b * 3 * NQ;
  float px[16], py[16], pz[16], dist[16];
#pragma unroll
  for (int s = 0; s < 16; s++) {
    int i = t + (s << 8);                      // strided ownership: idx = t + 256*s
    px[s] = xb[i]; py[s] = xb[NQ + i]; pz[s] = xb[2 * NQ + i];
  }
  float x0 = xb[0], y0 = xb[NQ], z0 = xb[2 * NQ];
#pragma unroll
  for (int s = 0; s < 16; s++) {
    float dx = px[s] - x0, dy = py[s] - y0, dz = pz[s] - z0;
    float a = dx * dx, bq = dy * dy, cq = dz * dz;
    dist[s] = (a + bq) + cq;                   // ((a+b)+c) like np.sum axis=-1, n=3
  }
  if (t == 0) fps[b * NPT] = 0;
  __shared__ float rv[4]; __shared__ int ri[4];
  __shared__ float wpt[3]; __shared__ int wid;
  for (int it = 1; it < NPT; it++) {
    // local argmax (strict > keeps lowest global index)
    float bv = dist[0]; int bs = 0;
#pragma unroll
    for (int s = 1; s < 16; s++) if (dist[s] > bv) { bv = dist[s]; bs = s; }
    int bidx = t + (bs << 8);
    // wave butterfly argmax, tie -> lower index
#pragma unroll
    for (int m = 1; m < 64; m <<= 1) {
      float ov = __shfl_xor(bv, m, 64);
      int oi = __shfl_xor(bidx, m, 64);
      if (ov > bv || (ov == bv && oi < bidx)) { bv = ov; bidx = oi; }
    }
    if ((t & 63) == 0) { rv[t >> 6] = bv; ri[t >> 6] = bidx; }
    __syncthreads();
    if (t == 0) {
      float v = rv[0]; int ii = ri[0];
      for (int w = 1; w < 4; w++)
        if (rv[w] > v || (rv[w] == v && ri[w] < ii)) { v = rv[w]; ii = ri[w]; }
      wid = ii;
      fps[b * NPT + it] = ii;
    }
    __syncthreads();
    int ii = wid;
    if ((ii & 255) == t) {
      int s = ii >> 8;
#pragma unroll
      for (int q2 = 0; q2 < 16; q2++)          // predicated: keep arrays in VGPRs
        if (q2 == s) { wpt[0] = px[q2]; wpt[1] = py[q2]; wpt[2] = pz[q2]; }
    }
    __syncthreads();
    float wx = wpt[0], wy = wpt[1], wz = wpt[2];
#pragma unroll
    for (int s = 0; s < 16; s++) {
      float dx = px[s] - wx, dy = py[s] - wy, dz = pz[s] - wz;
      float a = dx * dx, bq = dy * dy, cq = dz * dz;
      float d = (a + bq) + cq;
      dist[s] = fminf(dist[s], d);
    }
  }
}

// ---------- K4: GN statistics (sum, sumsq per (b,group)) over all h ----------
__global__ __launch_bounds__(256) void stats_kernel(const float* __restrict__ f8t,
                                                    const int* __restrict__ knn,
                                                    const float* __restrict__ w1,
                                                    double* __restrict__ stats) {
  __shared__ float fnb[16][132];   // [nl][k*8+c], +4 pad words -> 2-way banks (free)
  __shared__ float fqb[16][8];
  __shared__ float Alds[128][8];
  __shared__ float Dlds[128][8];
  int b = blockIdx.x >> 8;
  int n0 = (blockIdx.x & 255) << 4;
  int tid = threadIdx.x;
  if (tid < 128) {
#pragma unroll
    for (int c = 0; c < 8; c++) {
      float a = w1[tid * 16 + c];
      Alds[tid][c] = a;
      Dlds[tid][c] = w1[tid * 16 + 8 + c] - a;
    }
  }
  int nl = tid & 15, kk = tid >> 4;
  int nmy = n0 + nl;
  int idx = knn[(((size_t)(b << 12) + nmy) << 4) + kk];
  const float4* fp4 = (const float4*)(f8t + (((size_t)(b << 12) + idx) << 3));
  float4 v0 = fp4[0], v1 = fp4[1];
  float* dstp = &fnb[nl][kk << 3];
  ((float4*)dstp)[0] = v0;
  ((float4*)dstp)[1] = v1;
  if (tid < 16) {
    const float4* fq4 = (const float4*)(f8t + (((size_t)(b << 12) + n0 + tid) << 3));
    float4 a = fq4[0], c4 = fq4[1];
    fqb[tid][0] = a.x; fqb[tid][1] = a.y; fqb[tid][2] = a.z; fqb[tid][3] = a.w;
    fqb[tid][4] = c4.x; fqb[tid][5] = c4.y; fqb[tid][6] = c4.z; fqb[tid][7] = c4.w;
  }
  __syncthreads();
  int o8 = tid >> 4;
  int obase = o8 << 3;
  float fq[8];
#pragma unroll
  for (int c = 0; c < 8; c++) fq[c] = fqb[nl][c];
  float tv[8], Ar[64];
#pragma unroll
  for (int oo = 0; oo < 8; oo++) {
    float acc = 0.f;
#pragma unroll
    for (int c = 0; c < 8; c++) acc += Dlds[obase + oo][c] * fq[c];
    tv[oo] = acc;
#pragma unroll
    for (int c = 0; c < 8; c++) Ar[oo * 8 + c] = Alds[obase + oo][c];
  }
  float s = 0.f, s2 = 0.f;
  for (int k = 0; k < 16; k++) {
    float4 g0 = *(const float4*)&fnb[nl][k * 8];
    float4 g1 = *(const float4*)&fnb[nl][k * 8 + 4];
    float fn[8] = {g0.x, g0.y, g0.z, g0.w, g1.x, g1.y, g1.z, g1.w};
#pragma unroll
    for (int oo = 0; oo < 8; oo++) {
      float acc = tv[oo];
#pragma unroll
      for (int c = 0; c < 8; c++) acc += Ar[oo * 8 + c] * fn[c];
      s += acc; s2 += acc * acc;
    }
  }
  // wave = tid/64 maps exactly to group (o8/4)
#pragma unroll
  for (int m = 1; m < 64; m <<= 1) {
    s += __shfl_xor(s, m, 64);
    s2 += __shfl_xor(s2, m, 64);
  }
  if ((tid & 63) == 0) {
    int g = tid >> 6;
    atomicAdd(&stats[((b << 2) + g) * 2 + 0], (double)s);
    atomicAdd(&stats[((b << 2) + g) * 2 + 1], (double)s2);
  }
}

// ---------- K5: finalize mean/rstd ----------
__global__ void finalize_kernel(const double* __restrict__ stats, float* __restrict__ musd) {
  int i = threadIdx.x;
  if (i < 32) {
    double cnt = 2097152.0;                    // 32 * 4096 * 16
    double mean = stats[i * 2] / cnt;
    double var = stats[i * 2 + 1] / cnt - mean * mean;
    float rstd = (float)(1.0 / sqrt(var + 1e-5));
    musd[i * 2] = (float)mean;
    musd[i * 2 + 1] = rstd;
  }
}

// ---------- K6: recompute h for FPS-selected points, GN+leaky+max, write out1 ----------
__global__ __launch_bounds__(256) void out1_kernel(const float* __restrict__ f8t,
                                                   const int* __restrict__ knn,
                                                   const int* __restrict__ fps,
                                                   const float* __restrict__ w1,
                                                   const float* __restrict__ gnw,
                                                   const float* __restrict__ gnb,
                                                   const float* __restrict__ musd,
                                                   float* __restrict__ out1) {
  __shared__ float fnb[16][132];
  __shared__ float fqb[16][8];
  __shared__ float Alds[128][8];
  __shared__ float Dlds[128][8];
  int b = blockIdx.x >> 6;
  int j0 = (blockIdx.x & 63) << 4;
  int tid = threadIdx.x;
  if (tid < 128) {
#pragma unroll
    for (int c = 0; c < 8; c++) {
      float a = w1[tid * 16 + c];
      Alds[tid][c] = a;
      Dlds[tid][c] = w1[tid * 16 + 8 + c] - a;
    }
  }
  int nl = tid & 15, kk = tid >> 4;
  int nmy = fps[b * NPT + j0 + nl];
  int idx = knn[(((size_t)(b << 12) + nmy) << 4) + kk];
  const float4* fp4 = (const float4*)(f8t + (((size_t)(b << 12) + idx) << 3));
  float4 v0 = fp4[0], v1 = fp4[1];
  float* dstp = &fnb[nl][kk << 3];
  ((float4*)dstp)[0] = v0;
  ((float4*)dstp)[1] = v1;
  if (tid < 16) {
    int nq = fps[b * NPT + j0 + tid];
    const float4* fq4 = (const float4*)(f8t + (((size_t)(b << 12) + nq) << 3));
    float4 a = fq4[0], c4 = fq4[1];
    fqb[tid][0] = a.x; fqb[tid][1] = a.y; fqb[tid][2] = a.z; fqb[tid][3] = a.w;
    fqb[tid][4] = c4.x; fqb[tid][5] = c4.y; fqb[tid][6] = c4.z; fqb[tid][7] = c4.w;
  }
  __syncthreads();
  int o8 = tid >> 4;
  int obase = o8 << 3;
  float fq[8];
#pragma unroll
  for (int c = 0; c < 8; c++) fq[c] = fqb[nl][c];
  float tv[8], Ar[64];
#pragma unroll
  for (int oo = 0; oo < 8; oo++) {
    float acc = 0.f;
#pragma unroll
    for (int c = 0; c < 8; c++) acc += Dlds[obase + oo][c] * fq[c];
    tv[oo] = acc;
#pragma unroll
    for (int c = 0; c < 8; c++) Ar[oo * 8 + c] = Alds[obase + oo][c];
  }
  float mx[8], mn[8];
#pragma unroll
  for (int oo = 0; oo < 8; oo++) { mx[oo] = -3.4e38f; mn[oo] = 3.4e38f; }
  for (int k = 0; k < 16; k++) {
    float4 g0 = *(const float4*)&fnb[nl][k * 8];
    float4 g1 = *(const float4*)&fnb[nl][k * 8 + 4];
    float fn[8] = {g0.x, g0.y, g0.z, g0.w, g1.x, g1.y, g1.z, g1.w};
#pragma unroll
    for (int oo = 0; oo < 8; oo++) {
      float acc = tv[oo];
#pragma unroll
      for (int c = 0; c < 8; c++) acc += Ar[oo * 8 + c] * fn[c];
      mx[oo] = fmaxf(mx[oo], acc);
      mn[oo] = fminf(mn[oo], acc);
    }
  }
  int g = o8 >> 2;
  int j = j0 + nl;
  float mu = musd[((b << 2) + g) * 2];
  float rstd = musd[((b << 2) + g) * 2 + 1];
#pragma unroll
  for (int oo = 0; oo < 8; oo++) {
    int o = obase + oo;
    float w = gnw[o];
    // leaky(affine) is weakly monotone: slope>=0 -> use max_k h, else min_k h (exact)
    float v = (w >= 0.f) ? mx[oo] : mn[oo];
    float y = (v - mu) * rstd * w + gnb[o];
    y = (y >= 0.f) ? y : 0.2f * y;
    out1[(((size_t)b * 128 + o) << 10) + j] = y;
  }
}

// ---------- K7: coor gather + fps_idx as float ----------
__global__ __launch_bounds__(256) void gather_small_kernel(const float* __restrict__ x,
                                                           const int* __restrict__ fps,
                                                           float* __restrict__ out) {
  int t = blockIdx.x * 256 + threadIdx.x;   // 8192 = B*NPT
  int b = t >> 10, j = t & 1023;
  int i = fps[t];
  const float* xb = x + (size_t)b * 3 * NQ;
  out[((size_t)b * 3 + 0) * NPT + j] = xb[i];
  out[((size_t)b * 3 + 1) * NPT + j] = xb[NQ + i];
  out[((size_t)b * 3 + 2) * NPT + j] = xb[2 * NQ + i];
  out[24576 + 1048576 + t] = (float)i;      // fps_idx as float32
}

extern "C" void kernel_launch(void* const* d_in, const int* in_sizes, int n_in,
                              void* d_out, int out_size, void* d_ws, size_t ws_size,
                              hipStream_t stream) {
  const float* x    = (const float*)d_in[0];
  const float* f    = (const float*)d_in[1];
  const float* w_in = (const float*)d_in[2];
  const float* b_in = (const float*)d_in[3];
  const float* w1   = (const float*)d_in[4];
  const float* gnw  = (const float*)d_in[5];
  const float* gnb  = (const float*)d_in[6];
  float* out = (float*)d_out;

  char* ws = (char*)d_ws;
  float*  f8t   = (float*)(ws);                               // 1 MB
  int*    knn   = (int*)(ws + (1 << 20));                     // 2 MB
  int*    fps   = (int*)(ws + (3 << 20));                     // 32 KB
  double* stats = (double*)(ws + (3 << 20) + 32768);          // 512 B
  float*  musd  = (float*)(ws + (3 << 20) + 32768 + 512);     // 256 B

  f8_kernel<<<128, 256, 0, stream>>>(f, w_in, b_in, f8t);
  knn_kernel<<<256, 128, 0, stream>>>(x, knn);
  fps_kernel<<<8, 256, 0, stream>>>(x, fps);
  hipMemsetAsync(stats, 0, 512, stream);
  stats_kernel<<<2048, 256, 0, stream>>>(f8t, knn, w1, stats);
  finalize_kernel<<<1, 64, 0, stream>>>(stats, musd);
  out1_kernel<<<512, 256, 0, stream>>>(f8t, knn, fps, w1, gnw, gnb, musd, out + 24576);
  gather_small_kernel<<<32, 256, 0, stream>>>(x, fps, out);
}

// Round 2
// 1275.584 us; speedup vs baseline: 2.7447x; 2.7447x over previous
//
#include <hip/hip_runtime.h>

#define NQ 4096
#define NPT 1024
#define CAP 16

// ---------- K1: f8t[b][n][c] = (w_in @ f + b_in), layout (B, N, 8) ----------
__global__ __launch_bounds__(256) void f8_kernel(const float* __restrict__ f,
                                                 const float* __restrict__ w_in,
                                                 const float* __restrict__ b_in,
                                                 float* __restrict__ f8t) {
  int t = blockIdx.x * 256 + threadIdx.x;      // 0..32767  (b*4096+n)
  int b = t >> 12, n = t & 4095;
  const float* fb = f + (size_t)b * 3 * NQ + n;
  float f0 = fb[0], f1 = fb[NQ], f2 = fb[2 * NQ];
  float out[8];
#pragma unroll
  for (int o = 0; o < 8; o++) {
    out[o] = w_in[o * 3 + 0] * f0 + w_in[o * 3 + 1] * f1 + w_in[o * 3 + 2] * f2 + b_in[o];
  }
  float4* dst = (float4*)(f8t + ((size_t)t << 3));
  dst[0] = make_float4(out[0], out[1], out[2], out[3]);
  dst[1] = make_float4(out[4], out[5], out[6], out[7]);
}

// ---------- K2: kNN, lazy-queue top-16 (exact, numpy tie semantics) ----------
__global__ __launch_bounds__(128) void knn_kernel(const float* __restrict__ x,
                                                  int* __restrict__ knn) {
#pragma clang fp contract(off)
  __shared__ float4 pts[2048];                    // 32 KB candidate chunk
  __shared__ unsigned long long qbuf[128 * CAP];  // 16 KB per-lane queues
  int b = blockIdx.x >> 5;
  int n0 = (blockIdx.x & 31) << 7;
  int tid = threadIdx.x;
  const float* xb = x + (size_t)b * 3 * NQ;
  int n = n0 + tid;
  float qx = xb[n], qy = xb[NQ + n], qz = xb[2 * NQ + n];
  float qw = (qx * qx + qy * qy) + qz * qz;       // same formula as pts sq
  float bd[16]; int bi[16];
#pragma unroll
  for (int i = 0; i < 16; i++) { bd[i] = 3.4e38f; bi[i] = -1; }
  float thr = 3.4e38f;
  int cnt = 0;
  int qbase = tid * CAP;

  // sorted insert of (ed, em) into ascending bd/bi; requires ed < bd[15].
  // Per-slot independent (depth 2): ILP-friendly, no serial scan.
  auto insert16 = [&](float ed, int em) {
#pragma unroll
    for (int i2 = 15; i2 >= 1; --i2) {
      bool ltp = ed < bd[i2 - 1];
      bool ltc = ed < bd[i2];
      float nv = ltp ? bd[i2 - 1] : ed;
      int ni = ltp ? bi[i2 - 1] : em;
      bd[i2] = ltc ? nv : bd[i2];
      bi[i2] = ltc ? ni : bi[i2];
    }
    bool lt0 = ed < bd[0];
    bd[0] = lt0 ? ed : bd[0];
    bi[0] = lt0 ? em : bi[0];
  };
  auto drain = [&]() {
#pragma unroll 1
    for (int j = 0; j < cnt; j++) {             // divergent trip count is fine
      unsigned long long e = qbuf[qbase + j];
      float ed = __uint_as_float((unsigned int)(e >> 32));
      int em = (int)(e & 0xFFFFFFFFull);
      if (ed < bd[15]) insert16(ed, em);        // re-check vs current 16th
    }
    cnt = 0;
    thr = bd[15];
  };

  for (int c0 = 0; c0 < NQ; c0 += 2048) {
    __syncthreads();                            // protect pts from prior readers
    for (int i = tid; i < 2048; i += 128) {
      int g = c0 + i;
      float px = xb[g], py = xb[NQ + g], pz = xb[2 * NQ + g];
      float sq = (px * px + py * py) + pz * pz;
      pts[i] = make_float4(px, py, pz, sq);
    }
    __syncthreads();
    for (int m0 = 0; m0 < 2048; m0 += 8) {
      float4 p[8];
#pragma unroll
      for (int j = 0; j < 8; j++) p[j] = pts[m0 + j];   // batched b128 broadcasts
      float d[8];
#pragma unroll
      for (int j = 0; j < 8; j++) {
        float dot = (qx * p[j].x + qy * p[j].y) + qz * p[j].z;
        d[j] = (qw + p[j].w) - 2.0f * dot;
      }
#pragma unroll
      for (int j = 0; j < 8; j++) {
        if (d[j] < thr) {                       // cheap enqueue (stale thr ok)
          qbuf[qbase + cnt] =
              ((unsigned long long)__float_as_uint(d[j]) << 32) |
              (unsigned int)(c0 + m0 + j);
          cnt++;
        }
      }
      // cnt <= 8 guaranteed after this check; +8 next group => never > CAP
      if (__ballot(cnt > CAP - 8)) drain();
    }
  }
  drain();  // flush remaining entries

  int4* dst = (int4*)(knn + (((size_t)(b << 12) + n) << 4));
  dst[0] = make_int4(bi[0], bi[1], bi[2], bi[3]);
  dst[1] = make_int4(bi[4], bi[5], bi[6], bi[7]);
  dst[2] = make_int4(bi[8], bi[9], bi[10], bi[11]);
  dst[3] = make_int4(bi[12], bi[13], bi[14], bi[15]);
}

// ---------- K3: FPS, packed-u64 argmax, 1 barrier per iteration ----------
__global__ __launch_bounds__(256) void fps_kernel(const float* __restrict__ x,
                                                  int* __restrict__ fps) {
#pragma clang fp contract(off)
  __shared__ float ptsx[NQ], ptsy[NQ], ptsz[NQ];   // 48 KB winner-broadcast
  __shared__ unsigned long long red[2][4];          // double-buffered partials
  int b = blockIdx.x, t = threadIdx.x;
  const float* xb = x + (size_t)b * 3 * NQ;
  float px[16], py[16], pz[16], dist[16];
#pragma unroll
  for (int s = 0; s < 16; s++) {
    int i = (s << 8) + t;                           // strided ownership
    float X = xb[i], Y = xb[NQ + i], Z = xb[2 * NQ + i];
    px[s] = X; py[s] = Y; pz[s] = Z;
    ptsx[i] = X; ptsy[i] = Y; ptsz[i] = Z;
  }
  float x0 = xb[0], y0 = xb[NQ], z0 = xb[2 * NQ];
#pragma unroll
  for (int s = 0; s < 16; s++) {
    float dx = px[s] - x0, dy = py[s] - y0, dz = pz[s] - z0;
    float a = dx * dx, bq = dy * dy, cq = dz * dz;
    dist[s] = (a + bq) + cq;                        // ((a+b)+c), no fma
  }
  if (t == 0) fps[b * NPT] = 0;
  __syncthreads();
  for (int it = 1; it < NPT; it++) {
    // local argmax (strict > keeps lowest idx; s ascending = idx ascending)
    float mv = dist[0]; int mi = t;
#pragma unroll
    for (int s = 1; s < 16; s++) {
      int ii = (s << 8) + t;
      bool g = dist[s] > mv;
      mv = g ? dist[s] : mv;
      mi = g ? ii : mi;
    }
    // dist >= 0 always (sum of squares, min-chain) => float bits uint-monotone.
    // low word (4095-mi): max => lowest index, matching np.argmax tie-break.
    unsigned long long key = ((unsigned long long)__float_as_uint(mv) << 32) |
                             (unsigned int)(4095 - mi);
#pragma unroll
    for (int m = 1; m < 64; m <<= 1) {
      unsigned long long o = __shfl_xor(key, m, 64);
      key = (o > key) ? o : key;
    }
    int buf = it & 1;
    if ((t & 63) == 0) red[buf][t >> 6] = key;
    __syncthreads();   // single barrier: double buffer kills the WAR hazard
    unsigned long long k0 = red[buf][0], k1 = red[buf][1];
    unsigned long long k2 = red[buf][2], k3 = red[buf][3];
    k0 = (k1 > k0) ? k1 : k0;
    k2 = (k3 > k2) ? k3 : k2;
    k0 = (k2 > k0) ? k2 : k0;                       // every lane has the winner
    int wi = 4095 - (int)(k0 & 0xFFFFFFFFull);
    if (t == 0) fps[b * NPT + it] = wi;
    float wx = ptsx[wi], wy = ptsy[wi], wz = ptsz[wi];  // LDS broadcast
#pragma unroll
    for (int s = 0; s < 16; s++) {
      float dx = px[s] - wx, dy = py[s] - wy, dz = pz[s] - wz;
      float a = dx * dx, bq = dy * dy, cq = dz * dz;
      float d = (a + bq) + cq;
      dist[s] = fminf(dist[s], d);
    }
  }
}

// ---------- K4: GN statistics (sum, sumsq per (b,group)) over all h ----------
__global__ __launch_bounds__(256) void stats_kernel(const float* __restrict__ f8t,
                                                    const int* __restrict__ knn,
                                                    const float* __restrict__ w1,
                                                    double* __restrict__ stats) {
  __shared__ float fnb[16][132];   // [nl][k*8+c], +4 pad words
  __shared__ float fqb[16][8];
  __shared__ float Alds[128][8];
  __shared__ float Dlds[128][8];
  int b = blockIdx.x >> 8;
  int n0 = (blockIdx.x & 255) << 4;
  int tid = threadIdx.x;
  if (tid < 128) {
#pragma unroll
    for (int c = 0; c < 8; c++) {
      float a = w1[tid * 16 + c];
      Alds[tid][c] = a;
      Dlds[tid][c] = w1[tid * 16 + 8 + c] - a;
    }
  }
  int nl = tid & 15, kk = tid >> 4;
  int nmy = n0 + nl;
  int idx = knn[(((size_t)(b << 12) + nmy) << 4) + kk];
  const float4* fp4 = (const float4*)(f8t + (((size_t)(b << 12) + idx) << 3));
  float4 v0 = fp4[0], v1 = fp4[1];
  float* dstp = &fnb[nl][kk << 3];
  ((float4*)dstp)[0] = v0;
  ((float4*)dstp)[1] = v1;
  if (tid < 16) {
    const float4* fq4 = (const float4*)(f8t + (((size_t)(b << 12) + n0 + tid) << 3));
    float4 a = fq4[0], c4 = fq4[1];
    fqb[tid][0] = a.x; fqb[tid][1] = a.y; fqb[tid][2] = a.z; fqb[tid][3] = a.w;
    fqb[tid][4] = c4.x; fqb[tid][5] = c4.y; fqb[tid][6] = c4.z; fqb[tid][7] = c4.w;
  }
  __syncthreads();
  int o8 = tid >> 4;
  int obase = o8 << 3;
  float fq[8];
#pragma unroll
  for (int c = 0; c < 8; c++) fq[c] = fqb[nl][c];
  float tv[8], Ar[64];
#pragma unroll
  for (int oo = 0; oo < 8; oo++) {
    float acc = 0.f;
#pragma unroll
    for (int c = 0; c < 8; c++) acc += Dlds[obase + oo][c] * fq[c];
    tv[oo] = acc;
#pragma unroll
    for (int c = 0; c < 8; c++) Ar[oo * 8 + c] = Alds[obase + oo][c];
  }
  float s = 0.f, s2 = 0.f;
  for (int k = 0; k < 16; k++) {
    float4 g0 = *(const float4*)&fnb[nl][k * 8];
    float4 g1 = *(const float4*)&fnb[nl][k * 8 + 4];
    float fn[8] = {g0.x, g0.y, g0.z, g0.w, g1.x, g1.y, g1.z, g1.w};
#pragma unroll
    for (int oo = 0; oo < 8; oo++) {
      float acc = tv[oo];
#pragma unroll
      for (int c = 0; c < 8; c++) acc += Ar[oo * 8 + c] * fn[c];
      s += acc; s2 += acc * acc;
    }
  }
#pragma unroll
  for (int m = 1; m < 64; m <<= 1) {
    s += __shfl_xor(s, m, 64);
    s2 += __shfl_xor(s2, m, 64);
  }
  if ((tid & 63) == 0) {
    int g = tid >> 6;
    atomicAdd(&stats[((b << 2) + g) * 2 + 0], (double)s);
    atomicAdd(&stats[((b << 2) + g) * 2 + 1], (double)s2);
  }
}

// ---------- K5: finalize mean/rstd ----------
__global__ void finalize_kernel(const double* __restrict__ stats, float* __restrict__ musd) {
  int i = threadIdx.x;
  if (i < 32) {
    double cnt = 2097152.0;                    // 32 * 4096 * 16
    double mean = stats[i * 2] / cnt;
    double var = stats[i * 2 + 1] / cnt - mean * mean;
    float rstd = (float)(1.0 / sqrt(var + 1e-5));
    musd[i * 2] = (float)mean;
    musd[i * 2 + 1] = rstd;
  }
}

// ---------- K6: recompute h for FPS-selected points, GN+leaky+max, write out1 ----------
__global__ __launch_bounds__(256) void out1_kernel(const float* __restrict__ f8t,
                                                   const int* __restrict__ knn,
                                                   const int* __restrict__ fps,
                                                   const float* __restrict__ w1,
                                                   const float* __restrict__ gnw,
                                                   const float* __restrict__ gnb,
                                                   const float* __restrict__ musd,
                                                   float* __restrict__ out1) {
  __shared__ float fnb[16][132];
  __shared__ float fqb[16][8];
  __shared__ float Alds[128][8];
  __shared__ float Dlds[128][8];
  int b = blockIdx.x >> 6;
  int j0 = (blockIdx.x & 63) << 4;
  int tid = threadIdx.x;
  if (tid < 128) {
#pragma unroll
    for (int c = 0; c < 8; c++) {
      float a = w1[tid * 16 + c];
      Alds[tid][c] = a;
      Dlds[tid][c] = w1[tid * 16 + 8 + c] - a;
    }
  }
  int nl = tid & 15, kk = tid >> 4;
  int nmy = fps[b * NPT + j0 + nl];
  int idx = knn[(((size_t)(b << 12) + nmy) << 4) + kk];
  const float4* fp4 = (const float4*)(f8t + (((size_t)(b << 12) + idx) << 3));
  float4 v0 = fp4[0], v1 = fp4[1];
  float* dstp = &fnb[nl][kk << 3];
  ((float4*)dstp)[0] = v0;
  ((float4*)dstp)[1] = v1;
  if (tid < 16) {
    int nq = fps[b * NPT + j0 + tid];
    const float4* fq4 = (const float4*)(f8t + (((size_t)(b << 12) + nq) << 3));
    float4 a = fq4[0], c4 = fq4[1];
    fqb[tid][0] = a.x; fqb[tid][1] = a.y; fqb[tid][2] = a.z; fqb[tid][3] = a.w;
    fqb[tid][4] = c4.x; fqb[tid][5] = c4.y; fqb[tid][6] = c4.z; fqb[tid][7] = c4.w;
  }
  __syncthreads();
  int o8 = tid >> 4;
  int obase = o8 << 3;
  float fq[8];
#pragma unroll
  for (int c = 0; c < 8; c++) fq[c] = fqb[nl][c];
  float tv[8], Ar[64];
#pragma unroll
  for (int oo = 0; oo < 8; oo++) {
    float acc = 0.f;
#pragma unroll
    for (int c = 0; c < 8; c++) acc += Dlds[obase + oo][c] * fq[c];
    tv[oo] = acc;
#pragma unroll
    for (int c = 0; c < 8; c++) Ar[oo * 8 + c] = Alds[obase + oo][c];
  }
  float mx[8], mn[8];
#pragma unroll
  for (int oo = 0; oo < 8; oo++) { mx[oo] = -3.4e38f; mn[oo] = 3.4e38f; }
  for (int k = 0; k < 16; k++) {
    float4 g0 = *(const float4*)&fnb[nl][k * 8];
    float4 g1 = *(const float4*)&fnb[nl][k * 8 + 4];
    float fn[8] = {g0.x, g0.y, g0.z, g0.w, g1.x, g1.y, g1.z, g1.w};
#pragma unroll
    for (int oo = 0; oo < 8; oo++) {
      float acc = tv[oo];
#pragma unroll
      for (int c = 0; c < 8; c++) acc += Ar[oo * 8 + c] * fn[c];
      mx[oo] = fmaxf(mx[oo], acc);
      mn[oo] = fminf(mn[oo], acc);
    }
  }
  int g = o8 >> 2;
  int j = j0 + nl;
  float mu = musd[((b << 2) + g) * 2];
  float rstd = musd[((b << 2) + g) * 2 + 1];
#pragma unroll
  for (int oo = 0; oo < 8; oo++) {
    int o = obase + oo;
    float w = gnw[o];
    float v = (w >= 0.f) ? mx[oo] : mn[oo];   // leaky∘affine weakly monotone
    float y = (v - mu) * rstd * w + gnb[o];
    y = (y >= 0.f) ? y : 0.2f * y;
    out1[(((size_t)b * 128 + o) << 10) + j] = y;
  }
}

// ---------- K7: coor gather + fps_idx as float ----------
__global__ __launch_bounds__(256) void gather_small_kernel(const float* __restrict__ x,
                                                           const int* __restrict__ fps,
                                                           float* __restrict__ out) {
  int t = blockIdx.x * 256 + threadIdx.x;   // 8192 = B*NPT
  int b = t >> 10, j = t & 1023;
  int i = fps[t];
  const float* xb = x + (size_t)b * 3 * NQ;
  out[((size_t)b * 3 + 0) * NPT + j] = xb[i];
  out[((size_t)b * 3 + 1) * NPT + j] = xb[NQ + i];
  out[((size_t)b * 3 + 2) * NPT + j] = xb[2 * NQ + i];
  out[24576 + 1048576 + t] = (float)i;      // fps_idx as float32
}

extern "C" void kernel_launch(void* const* d_in, const int* in_sizes, int n_in,
                              void* d_out, int out_size, void* d_ws, size_t ws_size,
                              hipStream_t stream) {
  const float* x    = (const float*)d_in[0];
  const float* f    = (const float*)d_in[1];
  const float* w_in = (const float*)d_in[2];
  const float* b_in = (const float*)d_in[3];
  const float* w1   = (const float*)d_in[4];
  const float* gnw  = (const float*)d_in[5];
  const float* gnb  = (const float*)d_in[6];
  float* out = (float*)d_out;

  char* ws = (char*)d_ws;
  float*  f8t   = (float*)(ws);                               // 1 MB
  int*    knn   = (int*)(ws + (1 << 20));                     // 2 MB
  int*    fps   = (int*)(ws + (3 << 20));                     // 32 KB
  double* stats = (double*)(ws + (3 << 20) + 32768);          // 512 B
  float*  musd  = (float*)(ws + (3 << 20) + 32768 + 512);     // 256 B

  f8_kernel<<<128, 256, 0, stream>>>(f, w_in, b_in, f8t);
  knn_kernel<<<256, 128, 0, stream>>>(x, knn);
  fps_kernel<<<8, 256, 0, stream>>>(x, fps);
  hipMemsetAsync(stats, 0, 512, stream);
  stats_kernel<<<2048, 256, 0, stream>>>(f8t, knn, w1, stats);
  finalize_kernel<<<1, 64, 0, stream>>>(stats, musd);
  out1_kernel<<<512, 256, 0, stream>>>(f8t, knn, fps, w1, gnw, gnb, musd, out + 24576);
  gather_small_kernel<<<32, 256, 0, stream>>>(x, fps, out);
}

// Round 3
// 1015.621 us; speedup vs baseline: 3.4473x; 1.2560x over previous
//
#include <hip/hip_runtime.h>

#define NQ 4096
#define NPT 1024
#define CAP 16

struct KnnSm { float4 pts[2048]; unsigned long long qbuf[256 * CAP]; };  // 64 KB
struct FpsSm { float px[NQ], py[NQ], pz[NQ]; unsigned long long red[2][8]; };  // 48.1 KB
union FusedSm { KnnSm k; FpsSm f; };

// lexicographic max of (hi,lo) pairs across wave via DPP; result lands in lane 63.
// invalid lanes read (0,0) which is identity for our non-negative keys.
#define DPP_STEP(CTRL)                                                          \
  {                                                                             \
    unsigned sh = (unsigned)__builtin_amdgcn_update_dpp(0, (int)hi, CTRL, 0xF, 0xF, true); \
    unsigned sl = (unsigned)__builtin_amdgcn_update_dpp(0, (int)lo, CTRL, 0xF, 0xF, true); \
    bool tk = (sh > hi) || ((sh == hi) && (sl > lo));                           \
    hi = tk ? sh : hi;                                                          \
    lo = tk ? sl : lo;                                                          \
  }

__global__ __launch_bounds__(256) void fused_kernel(const float* __restrict__ x,
                                                    const float* __restrict__ f,
                                                    const float* __restrict__ w_in,
                                                    const float* __restrict__ b_in,
                                                    float* __restrict__ f8t,
                                                    int* __restrict__ knn,
                                                    int* __restrict__ fps,
                                                    double* __restrict__ stats) {
  __shared__ FusedSm sm;
  int tid = threadIdx.x;

  if (blockIdx.x < 8) {
    // ================= FPS (latency-optimized) =================
#pragma clang fp contract(off)
    int b = blockIdx.x;
    const float* xb = x + (size_t)b * 3 * NQ;
    float px[16], py[16], pz[16], dist[16];
#pragma unroll
    for (int s = 0; s < 16; s++) {
      int i = (s << 8) + tid;                       // strided ownership
      float X = xb[i], Y = xb[NQ + i], Z = xb[2 * NQ + i];
      px[s] = X; py[s] = Y; pz[s] = Z;
      sm.f.px[i] = X; sm.f.py[i] = Y; sm.f.pz[i] = Z;
    }
    float x0 = xb[0], y0 = xb[NQ], z0 = xb[2 * NQ];
#pragma unroll
    for (int s = 0; s < 16; s++) {
      float dx = px[s] - x0, dy = py[s] - y0, dz = pz[s] - z0;
      float a = dx * dx, bq = dy * dy, cq = dz * dz;
      dist[s] = (a + bq) + cq;                      // ((a+b)+c), no fma
    }
    if (tid == 0) fps[b * NPT] = 0;
    __syncthreads();
    for (int it = 1; it < NPT; it++) {
      // tree argmax over 16 slots; strict > keeps lower slot (= lower global idx)
      float tv[8]; int ts[8];
#pragma unroll
      for (int s = 0; s < 8; s++) {
        bool g = dist[2 * s + 1] > dist[2 * s];
        tv[s] = g ? dist[2 * s + 1] : dist[2 * s];
        ts[s] = g ? (2 * s + 1) : (2 * s);
      }
#pragma unroll
      for (int s = 0; s < 4; s++) {
        bool g = tv[2 * s + 1] > tv[2 * s];
        tv[s] = g ? tv[2 * s + 1] : tv[2 * s];
        ts[s] = g ? ts[2 * s + 1] : ts[2 * s];
      }
#pragma unroll
      for (int s = 0; s < 2; s++) {
        bool g = tv[2 * s + 1] > tv[2 * s];
        tv[s] = g ? tv[2 * s + 1] : tv[2 * s];
        ts[s] = g ? ts[2 * s + 1] : ts[2 * s];
      }
      bool gf = tv[1] > tv[0];
      float mv = gf ? tv[1] : tv[0];
      int ms = gf ? ts[1] : ts[0];
      // dist >= 0 => float bits are uint-monotone; lo = 4095-idx: max => lowest idx
      unsigned hi = __float_as_uint(mv);
      unsigned lo = 4095u - (unsigned)((ms << 8) + tid);
      DPP_STEP(0x111)  // row_shr:1
      DPP_STEP(0x112)  // row_shr:2
      DPP_STEP(0x114)  // row_shr:4
      DPP_STEP(0x118)  // row_shr:8
      DPP_STEP(0x142)  // row_bcast:15
      DPP_STEP(0x143)  // row_bcast:31  -> lane 63 holds wave max
      int buf = it & 1;
      if ((tid & 63) == 63)
        sm.f.red[buf][tid >> 6] = ((unsigned long long)hi << 32) | lo;
      __syncthreads();  // single barrier; double buffer kills WAR hazard
      unsigned long long k0 = sm.f.red[buf][0], k1 = sm.f.red[buf][1];
      unsigned long long k2 = sm.f.red[buf][2], k3 = sm.f.red[buf][3];
      k0 = (k1 > k0) ? k1 : k0;
      k2 = (k3 > k2) ? k3 : k2;
      k0 = (k2 > k0) ? k2 : k0;                     // every lane has the winner
      int wi = 4095 - (int)(unsigned)(k0 & 0xFFFFFFFFull);
      if (tid == 0) fps[b * NPT + it] = wi;
      float wx = sm.f.px[wi], wy = sm.f.py[wi], wz = sm.f.pz[wi];  // broadcast
#pragma unroll
      for (int s = 0; s < 16; s++) {
        float dx = px[s] - wx, dy = py[s] - wy, dz = pz[s] - wz;
        float a = dx * dx, bq = dy * dy, cq = dz * dz;
        dist[s] = fminf(dist[s], (a + bq) + cq);
      }
    }
  } else if (blockIdx.x < 136) {
    // ================= kNN, lazy-queue top-16 =================
#pragma clang fp contract(off)
    int rel = blockIdx.x - 8;
    int b = rel >> 4;
    int n0 = (rel & 15) << 8;
    const float* xb = x + (size_t)b * 3 * NQ;
    int n = n0 + tid;
    float qx = xb[n], qy = xb[NQ + n], qz = xb[2 * NQ + n];
    float qw = (qx * qx + qy * qy) + qz * qz;
    float bd[16]; int bi[16];
#pragma unroll
    for (int i = 0; i < 16; i++) { bd[i] = 3.4e38f; bi[i] = -1; }
    float thr = 3.4e38f;
    int cnt = 0;
    int qbase = tid * CAP;

    auto insert16 = [&](float ed, int em) {
#pragma unroll
      for (int i2 = 15; i2 >= 1; --i2) {
        bool ltp = ed < bd[i2 - 1];
        bool ltc = ed < bd[i2];
        float nv = ltp ? bd[i2 - 1] : ed;
        int ni = ltp ? bi[i2 - 1] : em;
        bd[i2] = ltc ? nv : bd[i2];
        bi[i2] = ltc ? ni : bi[i2];
      }
      bool lt0 = ed < bd[0];
      bd[0] = lt0 ? ed : bd[0];
      bi[0] = lt0 ? em : bi[0];
    };
    auto drain = [&]() {
#pragma unroll 1
      for (int j = 0; j < cnt; j++) {
        unsigned long long e = sm.k.qbuf[qbase + j];
        float ed = __uint_as_float((unsigned int)(e >> 32));
        int em = (int)(e & 0xFFFFFFFFull);
        if (ed < bd[15]) insert16(ed, em);
      }
      cnt = 0;
      thr = bd[15];
    };

    for (int c0 = 0; c0 < NQ; c0 += 2048) {
      __syncthreads();
      for (int i = tid; i < 2048; i += 256) {
        int g = c0 + i;
        float pxv = xb[g], pyv = xb[NQ + g], pzv = xb[2 * NQ + g];
        float sq = (pxv * pxv + pyv * pyv) + pzv * pzv;
        sm.k.pts[i] = make_float4(pxv, pyv, pzv, sq);
      }
      __syncthreads();
      for (int m0 = 0; m0 < 2048; m0 += 8) {
        float4 p[8];
#pragma unroll
        for (int j = 0; j < 8; j++) p[j] = sm.k.pts[m0 + j];
        float d[8];
#pragma unroll
        for (int j = 0; j < 8; j++) {
          float dot = (qx * p[j].x + qy * p[j].y) + qz * p[j].z;
          d[j] = (qw + p[j].w) - 2.0f * dot;
        }
#pragma unroll
        for (int j = 0; j < 8; j++) {
          if (d[j] < thr) {
            sm.k.qbuf[qbase + cnt] =
                ((unsigned long long)__float_as_uint(d[j]) << 32) |
                (unsigned int)(c0 + m0 + j);
            cnt++;
          }
        }
        if (__ballot(cnt > CAP - 8)) drain();
      }
    }
    drain();

    int4* dst = (int4*)(knn + (((size_t)(b << 12) + n) << 4));
    dst[0] = make_int4(bi[0], bi[1], bi[2], bi[3]);
    dst[1] = make_int4(bi[4], bi[5], bi[6], bi[7]);
    dst[2] = make_int4(bi[8], bi[9], bi[10], bi[11]);
    dst[3] = make_int4(bi[12], bi[13], bi[14], bi[15]);
  } else {
    // ================= f8 (1x1 conv) + stats zero-init =================
    int rel = blockIdx.x - 136;
    int t = rel * 256 + tid;                        // 0..32767
    int b = t >> 12, n = t & 4095;
    const float* fb = f + (size_t)b * 3 * NQ + n;
    float f0 = fb[0], f1 = fb[NQ], f2 = fb[2 * NQ];
    float out[8];
#pragma unroll
    for (int o = 0; o < 8; o++) {
      out[o] = w_in[o * 3 + 0] * f0 + w_in[o * 3 + 1] * f1 + w_in[o * 3 + 2] * f2 + b_in[o];
    }
    float4* dst = (float4*)(f8t + ((size_t)t << 3));
    dst[0] = make_float4(out[0], out[1], out[2], out[3]);
    dst[1] = make_float4(out[4], out[5], out[6], out[7]);
    if (rel == 0 && tid < 64) stats[tid] = 0.0;     // replaces memset launch
  }
}

// ---------- stats: GN sum/sumsq per (b,group) over all h ----------
__global__ __launch_bounds__(256) void stats_kernel(const float* __restrict__ f8t,
                                                    const int* __restrict__ knn,
                                                    const float* __restrict__ w1,
                                                    double* __restrict__ stats) {
  __shared__ float fnb[16][132];
  __shared__ float fqb[16][8];
  __shared__ float Alds[128][8];
  __shared__ float Dlds[128][8];
  int b = blockIdx.x >> 8;
  int n0 = (blockIdx.x & 255) << 4;
  int tid = threadIdx.x;
  if (tid < 128) {
#pragma unroll
    for (int c = 0; c < 8; c++) {
      float a = w1[tid * 16 + c];
      Alds[tid][c] = a;
      Dlds[tid][c] = w1[tid * 16 + 8 + c] - a;
    }
  }
  int nl = tid & 15, kk = tid >> 4;
  int nmy = n0 + nl;
  int idx = knn[(((size_t)(b << 12) + nmy) << 4) + kk];
  const float4* fp4 = (const float4*)(f8t + (((size_t)(b << 12) + idx) << 3));
  float4 v0 = fp4[0], v1 = fp4[1];
  float* dstp = &fnb[nl][kk << 3];
  ((float4*)dstp)[0] = v0;
  ((float4*)dstp)[1] = v1;
  if (tid < 16) {
    const float4* fq4 = (const float4*)(f8t + (((size_t)(b << 12) + n0 + tid) << 3));
    float4 a = fq4[0], c4 = fq4[1];
    fqb[tid][0] = a.x; fqb[tid][1] = a.y; fqb[tid][2] = a.z; fqb[tid][3] = a.w;
    fqb[tid][4] = c4.x; fqb[tid][5] = c4.y; fqb[tid][6] = c4.z; fqb[tid][7] = c4.w;
  }
  __syncthreads();
  int o8 = tid >> 4;
  int obase = o8 << 3;
  float fq[8];
#pragma unroll
  for (int c = 0; c < 8; c++) fq[c] = fqb[nl][c];
  float tv[8], Ar[64];
#pragma unroll
  for (int oo = 0; oo < 8; oo++) {
    float acc = 0.f;
#pragma unroll
    for (int c = 0; c < 8; c++) acc += Dlds[obase + oo][c] * fq[c];
    tv[oo] = acc;
#pragma unroll
    for (int c = 0; c < 8; c++) Ar[oo * 8 + c] = Alds[obase + oo][c];
  }
  float s = 0.f, s2 = 0.f;
  for (int k = 0; k < 16; k++) {
    float4 g0 = *(const float4*)&fnb[nl][k * 8];
    float4 g1 = *(const float4*)&fnb[nl][k * 8 + 4];
    float fn[8] = {g0.x, g0.y, g0.z, g0.w, g1.x, g1.y, g1.z, g1.w};
#pragma unroll
    for (int oo = 0; oo < 8; oo++) {
      float acc = tv[oo];
#pragma unroll
      for (int c = 0; c < 8; c++) acc += Ar[oo * 8 + c] * fn[c];
      s += acc; s2 += acc * acc;
    }
  }
#pragma unroll
  for (int m = 1; m < 64; m <<= 1) {
    s += __shfl_xor(s, m, 64);
    s2 += __shfl_xor(s2, m, 64);
  }
  if ((tid & 63) == 0) {
    int g = tid >> 6;
    atomicAdd(&stats[((b << 2) + g) * 2 + 0], (double)s);
    atomicAdd(&stats[((b << 2) + g) * 2 + 1], (double)s2);
  }
}

// ---------- finalize mean/rstd ----------
__global__ void finalize_kernel(const double* __restrict__ stats, float* __restrict__ musd) {
  int i = threadIdx.x;
  if (i < 32) {
    double cnt = 2097152.0;                    // 32 * 4096 * 16
    double mean = stats[i * 2] / cnt;
    double var = stats[i * 2 + 1] / cnt - mean * mean;
    float rstd = (float)(1.0 / sqrt(var + 1e-5));
    musd[i * 2] = (float)mean;
    musd[i * 2 + 1] = rstd;
  }
}

// ---------- out1 (recompute h for selected, GN+leaky+max) + coor/idx gather ----------
__global__ __launch_bounds__(256) void out1_gather_kernel(const float* __restrict__ x,
                                                          const float* __restrict__ f8t,
                                                          const int* __restrict__ knn,
                                                          const int* __restrict__ fps,
                                                          const float* __restrict__ w1,
                                                          const float* __restrict__ gnw,
                                                          const float* __restrict__ gnb,
                                                          const float* __restrict__ musd,
                                                          float* __restrict__ out) {
  __shared__ float fnb[16][132];
  __shared__ float fqb[16][8];
  __shared__ float Alds[128][8];
  __shared__ float Dlds[128][8];
  int tid = threadIdx.x;
  if (blockIdx.x >= 512) {
    // gather: coor + fps_idx as float
    int t = (blockIdx.x - 512) * 256 + tid;   // 8192 = B*NPT
    int b = t >> 10, j = t & 1023;
    int i = fps[t];
    const float* xb = x + (size_t)b * 3 * NQ;
    out[((size_t)b * 3 + 0) * NPT + j] = xb[i];
    out[((size_t)b * 3 + 1) * NPT + j] = xb[NQ + i];
    out[((size_t)b * 3 + 2) * NPT + j] = xb[2 * NQ + i];
    out[24576 + 1048576 + t] = (float)i;
    return;
  }
  float* out1 = out + 24576;
  int b = blockIdx.x >> 6;
  int j0 = (blockIdx.x & 63) << 4;
  if (tid < 128) {
#pragma unroll
    for (int c = 0; c < 8; c++) {
      float a = w1[tid * 16 + c];
      Alds[tid][c] = a;
      Dlds[tid][c] = w1[tid * 16 + 8 + c] - a;
    }
  }
  int nl = tid & 15, kk = tid >> 4;
  int nmy = fps[b * NPT + j0 + nl];
  int idx = knn[(((size_t)(b << 12) + nmy) << 4) + kk];
  const float4* fp4 = (const float4*)(f8t + (((size_t)(b << 12) + idx) << 3));
  float4 v0 = fp4[0], v1 = fp4[1];
  float* dstp = &fnb[nl][kk << 3];
  ((float4*)dstp)[0] = v0;
  ((float4*)dstp)[1] = v1;
  if (tid < 16) {
    int nq = fps[b * NPT + j0 + tid];
    const float4* fq4 = (const float4*)(f8t + (((size_t)(b << 12) + nq) << 3));
    float4 a = fq4[0], c4 = fq4[1];
    fqb[tid][0] = a.x; fqb[tid][1] = a.y; fqb[tid][2] = a.z; fqb[tid][3] = a.w;
    fqb[tid][4] = c4.x; fqb[tid][5] = c4.y; fqb[tid][6] = c4.z; fqb[tid][7] = c4.w;
  }
  __syncthreads();
  int o8 = tid >> 4;
  int obase = o8 << 3;
  float fq[8];
#pragma unroll
  for (int c = 0; c < 8; c++) fq[c] = fqb[nl][c];
  float tv[8], Ar[64];
#pragma unroll
  for (int oo = 0; oo < 8; oo++) {
    float acc = 0.f;
#pragma unroll
    for (int c = 0; c < 8; c++) acc += Dlds[obase + oo][c] * fq[c];
    tv[oo] = acc;
#pragma unroll
    for (int c = 0; c < 8; c++) Ar[oo * 8 + c] = Alds[obase + oo][c];
  }
  float mx[8], mn[8];
#pragma unroll
  for (int oo = 0; oo < 8; oo++) { mx[oo] = -3.4e38f; mn[oo] = 3.4e38f; }
  for (int k = 0; k < 16; k++) {
    float4 g0 = *(const float4*)&fnb[nl][k * 8];
    float4 g1 = *(const float4*)&fnb[nl][k * 8 + 4];
    float fn[8] = {g0.x, g0.y, g0.z, g0.w, g1.x, g1.y, g1.z, g1.w};
#pragma unroll
    for (int oo = 0; oo < 8; oo++) {
      float acc = tv[oo];
#pragma unroll
      for (int c = 0; c < 8; c++) acc += Ar[oo * 8 + c] * fn[c];
      mx[oo] = fmaxf(mx[oo], acc);
      mn[oo] = fminf(mn[oo], acc);
    }
  }
  int g = o8 >> 2;
  int j = j0 + nl;
  float mu = musd[((b << 2) + g) * 2];
  float rstd = musd[((b << 2) + g) * 2 + 1];
#pragma unroll
  for (int oo = 0; oo < 8; oo++) {
    int o = obase + oo;
    float w = gnw[o];
    float v = (w >= 0.f) ? mx[oo] : mn[oo];   // leaky∘affine weakly monotone
    float y = (v - mu) * rstd * w + gnb[o];
    y = (y >= 0.f) ? y : 0.2f * y;
    out1[(((size_t)b * 128 + o) << 10) + j] = y;
  }
}

extern "C" void kernel_launch(void* const* d_in, const int* in_sizes, int n_in,
                              void* d_out, int out_size, void* d_ws, size_t ws_size,
                              hipStream_t stream) {
  const float* x    = (const float*)d_in[0];
  const float* f    = (const float*)d_in[1];
  const float* w_in = (const float*)d_in[2];
  const float* b_in = (const float*)d_in[3];
  const float* w1   = (const float*)d_in[4];
  const float* gnw  = (const float*)d_in[5];
  const float* gnb  = (const float*)d_in[6];
  float* out = (float*)d_out;

  char* ws = (char*)d_ws;
  float*  f8t   = (float*)(ws);                               // 1 MB
  int*    knn   = (int*)(ws + (1 << 20));                     // 2 MB
  int*    fps   = (int*)(ws + (3 << 20));                     // 32 KB
  double* stats = (double*)(ws + (3 << 20) + 32768);          // 512 B
  float*  musd  = (float*)(ws + (3 << 20) + 32768 + 512);     // 256 B

  fused_kernel<<<264, 256, 0, stream>>>(x, f, w_in, b_in, f8t, knn, fps, stats);
  stats_kernel<<<2048, 256, 0, stream>>>(f8t, knn, w1, stats);
  finalize_kernel<<<1, 64, 0, stream>>>(stats, musd);
  out1_gather_kernel<<<544, 256, 0, stream>>>(x, f8t, knn, fps, w1, gnw, gnb, musd, out);
}

// Round 4
// 940.406 us; speedup vs baseline: 3.7230x; 1.0800x over previous
//
#include <hip/hip_runtime.h>

#define NQ 4096
#define NPT 1024
#define CAP 16

typedef float vf2 __attribute__((ext_vector_type(2)));

struct KnnSm { float4 pts[2048]; unsigned long long qbuf[CAP * 256]; };        // 64 KB
struct FpsSm { float px[NQ], py[NQ], pz[NQ]; unsigned long long red[2][4]; };  // 48.06 KB
struct GemmSm {
  float fnb[16][132]; float fqb[16][8]; float Alds[128][8]; float Dlds[128][8];
  int last;
};
union FusedSm { KnnSm k; FpsSm f; GemmSm g; };

struct Ctl { int f8_done, knn_done, fps_done, stats_done, fin_done, pad0, pad1, pad2;
             int fps_prog[8]; };   // 64 B, zeroed by memset each launch

// lexicographic max of (hi,lo) across wave via DPP; result in lane 63.
// bound_ctrl=true: invalid lanes read (0,0) = identity for non-negative keys.
#define DPP_STEP(CTRL)                                                          \
  {                                                                             \
    unsigned sh = (unsigned)__builtin_amdgcn_update_dpp(0, (int)hi, CTRL, 0xF, 0xF, true); \
    unsigned sl = (unsigned)__builtin_amdgcn_update_dpp(0, (int)lo, CTRL, 0xF, 0xF, true); \
    bool tk = (sh > hi) || ((sh == hi) && (sl > lo));                           \
    hi = tk ? sh : hi;                                                          \
    lo = tk ? sl : lo;                                                          \
  }

__device__ inline void spin_ge(int* p, int target) {
  while (__hip_atomic_load(p, __ATOMIC_RELAXED, __HIP_MEMORY_SCOPE_AGENT) < target)
    __builtin_amdgcn_s_sleep(16);
}
__device__ inline void release_inc(int* p) {
  __threadfence();   // make this block's global writes visible device-wide
  __hip_atomic_fetch_add(p, 1, __ATOMIC_RELAXED, __HIP_MEMORY_SCOPE_AGENT);
}

__global__ __launch_bounds__(256) void mega_kernel(
    const float* __restrict__ x, const float* __restrict__ f,
    const float* __restrict__ w_in, const float* __restrict__ b_in,
    const float* __restrict__ w1, const float* __restrict__ gnw,
    const float* __restrict__ gnb, float* __restrict__ f8t,
    int* __restrict__ knn, int* __restrict__ fps_g, double* __restrict__ stats,
    float* __restrict__ musd, Ctl* __restrict__ ctl, float* __restrict__ out) {
  __shared__ FusedSm sm;
  int tid = threadIdx.x;
  int bk = blockIdx.x;

  if (bk < 8) {
    // ================= FPS: packed update, DPP reduce, progress publish ======
#pragma clang fp contract(off)
    int b = bk;
    const float* xb = x + (size_t)b * 3 * NQ;
    vf2 px2[8], py2[8], pz2[8], d2[8];
#pragma unroll
    for (int p = 0; p < 8; p++) {
      int i0 = (p << 9) + tid, i1 = i0 + 256;
      float X0 = xb[i0], Y0 = xb[NQ + i0], Z0 = xb[2 * NQ + i0];
      float X1 = xb[i1], Y1 = xb[NQ + i1], Z1 = xb[2 * NQ + i1];
      px2[p] = vf2{X0, X1}; py2[p] = vf2{Y0, Y1}; pz2[p] = vf2{Z0, Z1};
      sm.f.px[i0] = X0; sm.f.py[i0] = Y0; sm.f.pz[i0] = Z0;
      sm.f.px[i1] = X1; sm.f.py[i1] = Y1; sm.f.pz[i1] = Z1;
    }
    float x0 = xb[0], y0 = xb[NQ], z0 = xb[2 * NQ];
    {
      vf2 wxv = vf2{x0, x0}, wyv = vf2{y0, y0}, wzv = vf2{z0, z0};
#pragma unroll
      for (int p = 0; p < 8; p++) {
        vf2 dx = px2[p] - wxv, dy = py2[p] - wyv, dz = pz2[p] - wzv;
        vf2 a = dx * dx, bq = dy * dy, cq = dz * dz;
        d2[p] = (a + bq) + cq;                      // ((a+b)+c) per element, no fma
      }
    }
    if (tid == 0) fps_g[b * NPT] = 0;
    __syncthreads();
    for (int it = 1; it < NPT; it++) {
      // tree argmax over 16 slots; strict > keeps lower slot (= lower global idx)
      float tv[8]; int ts[8];
#pragma unroll
      for (int s = 0; s < 8; s++) {
        float a = d2[s].x, bb = d2[s].y;
        bool g = bb > a;
        tv[s] = g ? bb : a;
        ts[s] = g ? (2 * s + 1) : (2 * s);
      }
#pragma unroll
      for (int s = 0; s < 4; s++) {
        bool g = tv[2 * s + 1] > tv[2 * s];
        tv[s] = g ? tv[2 * s + 1] : tv[2 * s];
        ts[s] = g ? ts[2 * s + 1] : ts[2 * s];
      }
#pragma unroll
      for (int s = 0; s < 2; s++) {
        bool g = tv[2 * s + 1] > tv[2 * s];
        tv[s] = g ? tv[2 * s + 1] : tv[2 * s];
        ts[s] = g ? ts[2 * s + 1] : ts[2 * s];
      }
      bool gf = tv[1] > tv[0];
      float mv = gf ? tv[1] : tv[0];
      int ms = gf ? ts[1] : ts[0];
      unsigned hi = __float_as_uint(mv);            // dist>=0: bits uint-monotone
      unsigned lo = 4095u - (unsigned)((ms << 8) + tid);  // max => lowest idx
      DPP_STEP(0x111)  // row_shr:1
      DPP_STEP(0x112)  // row_shr:2
      DPP_STEP(0x114)  // row_shr:4
      DPP_STEP(0x118)  // row_shr:8
      DPP_STEP(0x142)  // row_bcast:15
      DPP_STEP(0x143)  // row_bcast:31  -> lane 63 holds wave max
      int buf = it & 1;
      if ((tid & 63) == 63)
        sm.f.red[buf][tid >> 6] = ((unsigned long long)hi << 32) | lo;
      __syncthreads();  // single barrier; double buffer kills WAR hazard
      unsigned long long k0 = sm.f.red[buf][0], k1 = sm.f.red[buf][1];
      unsigned long long k2 = sm.f.red[buf][2], k3 = sm.f.red[buf][3];
      k0 = (k1 > k0) ? k1 : k0;
      k2 = (k3 > k2) ? k3 : k2;
      k0 = (k2 > k0) ? k2 : k0;                     // every lane has the winner
      int wi = 4095 - (int)(unsigned)(k0 & 0xFFFFFFFFull);
      if (tid == 0) {
        fps_g[b * NPT + it] = wi;
        if (((it + 1) & 63) == 0) {                 // publish prefix progress
          __threadfence();
          __hip_atomic_store(&ctl->fps_prog[b], it, __ATOMIC_RELAXED,
                             __HIP_MEMORY_SCOPE_AGENT);
        }
      }
      float wx = sm.f.px[wi], wy = sm.f.py[wi], wz = sm.f.pz[wi];  // broadcast
      vf2 wxv = vf2{wx, wx}, wyv = vf2{wy, wy}, wzv = vf2{wz, wz};
#pragma unroll
      for (int p = 0; p < 8; p++) {
        vf2 dx = px2[p] - wxv, dy = py2[p] - wyv, dz = pz2[p] - wzv;
        vf2 a = dx * dx, bq = dy * dy, cq = dz * dz;
        vf2 d = (a + bq) + cq;
        d2[p].x = fminf(d2[p].x, d.x);
        d2[p].y = fminf(d2[p].y, d.y);
      }
    }
    __syncthreads();
    if (tid == 0) release_inc(&ctl->fps_done);
  } else if (bk < 136) {
    // ================= kNN, lazy-queue top-16 (transposed queue) =============
#pragma clang fp contract(off)
    int rel = bk - 8;
    int b = rel >> 4;
    int n0 = (rel & 15) << 8;
    const float* xb = x + (size_t)b * 3 * NQ;
    int n = n0 + tid;
    float qx = xb[n], qy = xb[NQ + n], qz = xb[2 * NQ + n];
    float qw = (qx * qx + qy * qy) + qz * qz;
    float bd[16]; int bi[16];
#pragma unroll
    for (int i = 0; i < 16; i++) { bd[i] = 3.4e38f; bi[i] = -1; }
    float thr = 3.4e38f;
    int cnt = 0;

    auto insert16 = [&](float ed, int em) {
#pragma unroll
      for (int i2 = 15; i2 >= 1; --i2) {
        bool ltp = ed < bd[i2 - 1];
        bool ltc = ed < bd[i2];
        float nv = ltp ? bd[i2 - 1] : ed;
        int ni = ltp ? bi[i2 - 1] : em;
        bd[i2] = ltc ? nv : bd[i2];
        bi[i2] = ltc ? ni : bi[i2];
      }
      bool lt0 = ed < bd[0];
      bd[0] = lt0 ? ed : bd[0];
      bi[0] = lt0 ? em : bi[0];
    };
    auto drain = [&]() {
#pragma unroll 1
      for (int j = 0; j < cnt; j++) {
        unsigned long long e = sm.k.qbuf[j * 256 + tid];   // transposed: ~no conflicts
        float ed = __uint_as_float((unsigned int)(e >> 32));
        int em = (int)(e & 0xFFFFFFFFull);
        if (ed < bd[15]) insert16(ed, em);
      }
      cnt = 0;
      thr = bd[15];
    };

    for (int c0 = 0; c0 < NQ; c0 += 2048) {
      __syncthreads();
      for (int i = tid; i < 2048; i += 256) {
        int g = c0 + i;
        float pxv = xb[g], pyv = xb[NQ + g], pzv = xb[2 * NQ + g];
        float sq = (pxv * pxv + pyv * pyv) + pzv * pzv;
        sm.k.pts[i] = make_float4(pxv, pyv, pzv, sq);
      }
      __syncthreads();
      for (int m0 = 0; m0 < 2048; m0 += 8) {
        float4 p[8];
#pragma unroll
        for (int j = 0; j < 8; j++) p[j] = sm.k.pts[m0 + j];
        float d[8];
#pragma unroll
        for (int j = 0; j < 8; j++) {
          float dot = (qx * p[j].x + qy * p[j].y) + qz * p[j].z;
          d[j] = (qw + p[j].w) - 2.0f * dot;
        }
#pragma unroll
        for (int j = 0; j < 8; j++) {
          if (d[j] < thr) {
            sm.k.qbuf[cnt * 256 + tid] =
                ((unsigned long long)__float_as_uint(d[j]) << 32) |
                (unsigned int)(c0 + m0 + j);
            cnt++;
          }
        }
        if (__ballot(cnt > CAP - 8)) drain();
      }
    }
    drain();

    int4* dst = (int4*)(knn + (((size_t)(b << 12) + n) << 4));
    dst[0] = make_int4(bi[0], bi[1], bi[2], bi[3]);
    dst[1] = make_int4(bi[4], bi[5], bi[6], bi[7]);
    dst[2] = make_int4(bi[8], bi[9], bi[10], bi[11]);
    dst[3] = make_int4(bi[12], bi[13], bi[14], bi[15]);
    __syncthreads();
    if (tid == 0) release_inc(&ctl->knn_done);
  } else if (bk < 264) {
    // ================= f8 (1x1 conv) ========================================
    int rel = bk - 136;
    int t = rel * 256 + tid;
    int b = t >> 12, n = t & 4095;
    const float* fb = f + (size_t)b * 3 * NQ + n;
    float f0 = fb[0], f1 = fb[NQ], f2 = fb[2 * NQ];
    float o8v[8];
#pragma unroll
    for (int o = 0; o < 8; o++) {
      o8v[o] = w_in[o * 3 + 0] * f0 + w_in[o * 3 + 1] * f1 + w_in[o * 3 + 2] * f2 + b_in[o];
    }
    float4* dst = (float4*)(f8t + ((size_t)t << 3));
    dst[0] = make_float4(o8v[0], o8v[1], o8v[2], o8v[3]);
    dst[1] = make_float4(o8v[4], o8v[5], o8v[6], o8v[7]);
    __syncthreads();
    if (tid == 0) release_inc(&ctl->f8_done);
  } else if (bk < 2312) {
    // ================= stats (+ inline finalize in last block) ==============
    if (tid == 0) { spin_ge(&ctl->knn_done, 128); spin_ge(&ctl->f8_done, 128); }
    __syncthreads();
    __threadfence();   // acquire: invalidate L1 before reading knn/f8t
    int rel = bk - 264;
    int b = rel >> 8;
    int n0 = (rel & 255) << 4;
    if (tid < 128) {
#pragma unroll
      for (int c = 0; c < 8; c++) {
        float a = w1[tid * 16 + c];
        sm.g.Alds[tid][c] = a;
        sm.g.Dlds[tid][c] = w1[tid * 16 + 8 + c] - a;
      }
    }
    int nl = tid & 15, kk = tid >> 4;
    int nmy = n0 + nl;
    int idx = knn[(((size_t)(b << 12) + nmy) << 4) + kk];
    const float4* fp4 = (const float4*)(f8t + (((size_t)(b << 12) + idx) << 3));
    float4 v0 = fp4[0], v1 = fp4[1];
    float* dstp = &sm.g.fnb[nl][kk << 3];
    ((float4*)dstp)[0] = v0;
    ((float4*)dstp)[1] = v1;
    if (tid < 16) {
      const float4* fq4 = (const float4*)(f8t + (((size_t)(b << 12) + n0 + tid) << 3));
      float4 a = fq4[0], c4 = fq4[1];
      sm.g.fqb[tid][0] = a.x; sm.g.fqb[tid][1] = a.y; sm.g.fqb[tid][2] = a.z; sm.g.fqb[tid][3] = a.w;
      sm.g.fqb[tid][4] = c4.x; sm.g.fqb[tid][5] = c4.y; sm.g.fqb[tid][6] = c4.z; sm.g.fqb[tid][7] = c4.w;
    }
    __syncthreads();
    int o8 = tid >> 4;
    int obase = o8 << 3;
    float fq[8];
#pragma unroll
    for (int c = 0; c < 8; c++) fq[c] = sm.g.fqb[nl][c];
    float tv[8], Ar[64];
#pragma unroll
    for (int oo = 0; oo < 8; oo++) {
      float acc = 0.f;
#pragma unroll
      for (int c = 0; c < 8; c++) acc += sm.g.Dlds[obase + oo][c] * fq[c];
      tv[oo] = acc;
#pragma unroll
      for (int c = 0; c < 8; c++) Ar[oo * 8 + c] = sm.g.Alds[obase + oo][c];
    }
    float s = 0.f, s2 = 0.f;
    for (int k = 0; k < 16; k++) {
      float4 g0 = *(const float4*)&sm.g.fnb[nl][k * 8];
      float4 g1 = *(const float4*)&sm.g.fnb[nl][k * 8 + 4];
      float fn[8] = {g0.x, g0.y, g0.z, g0.w, g1.x, g1.y, g1.z, g1.w};
#pragma unroll
      for (int oo = 0; oo < 8; oo++) {
        float acc = tv[oo];
#pragma unroll
        for (int c = 0; c < 8; c++) acc += Ar[oo * 8 + c] * fn[c];
        s += acc; s2 += acc * acc;
      }
    }
#pragma unroll
    for (int m = 1; m < 64; m <<= 1) {
      s += __shfl_xor(s, m, 64);
      s2 += __shfl_xor(s2, m, 64);
    }
    if ((tid & 63) == 0) {
      int g = tid >> 6;
      atomicAdd(&stats[((b << 2) + g) * 2 + 0], (double)s);
      atomicAdd(&stats[((b << 2) + g) * 2 + 1], (double)s2);
    }
    __syncthreads();
    if (tid == 0) {
      __threadfence();
      int old = __hip_atomic_fetch_add(&ctl->stats_done, 1, __ATOMIC_ACQ_REL,
                                       __HIP_MEMORY_SCOPE_AGENT);
      sm.g.last = (old == 2047);
    }
    __syncthreads();
    if (sm.g.last) {
      if (tid < 32) {
        unsigned long long r0 = __hip_atomic_load((unsigned long long*)&stats[tid * 2],
                                                  __ATOMIC_RELAXED, __HIP_MEMORY_SCOPE_AGENT);
        unsigned long long r1 = __hip_atomic_load((unsigned long long*)&stats[tid * 2 + 1],
                                                  __ATOMIC_RELAXED, __HIP_MEMORY_SCOPE_AGENT);
        double cnt = 2097152.0;                     // 32 * 4096 * 16
        double mean = __longlong_as_double((long long)r0) / cnt;
        double var = __longlong_as_double((long long)r1) / cnt - mean * mean;
        float rstd = (float)(1.0 / sqrt(var + 1e-5));
        musd[tid * 2] = (float)mean;
        musd[tid * 2 + 1] = rstd;
      }
      __syncthreads();
      if (tid == 0) release_inc(&ctl->fin_done);
    }
  } else if (bk < 2824) {
    // ================= out1: recompute h for selected, GN+leaky+max =========
    int rel = bk - 2312;
    int b = rel >> 6;
    int j0 = (rel & 63) << 4;
    if (tid == 0) {
      spin_ge(&ctl->fps_prog[b], j0 + 15);          // only need fps prefix
      spin_ge(&ctl->fin_done, 1);
    }
    __syncthreads();
    __threadfence();
    float* out1 = out + 24576;
    if (tid < 128) {
#pragma unroll
      for (int c = 0; c < 8; c++) {
        float a = w1[tid * 16 + c];
        sm.g.Alds[tid][c] = a;
        sm.g.Dlds[tid][c] = w1[tid * 16 + 8 + c] - a;
      }
    }
    int nl = tid & 15, kk = tid >> 4;
    int nmy = fps_g[b * NPT + j0 + nl];
    int idx = knn[(((size_t)(b << 12) + nmy) << 4) + kk];
    const float4* fp4 = (const float4*)(f8t + (((size_t)(b << 12) + idx) << 3));
    float4 v0 = fp4[0], v1 = fp4[1];
    float* dstp = &sm.g.fnb[nl][kk << 3];
    ((float4*)dstp)[0] = v0;
    ((float4*)dstp)[1] = v1;
    if (tid < 16) {
      int nq = fps_g[b * NPT + j0 + tid];
      const float4* fq4 = (const float4*)(f8t + (((size_t)(b << 12) + nq) << 3));
      float4 a = fq4[0], c4 = fq4[1];
      sm.g.fqb[tid][0] = a.x; sm.g.fqb[tid][1] = a.y; sm.g.fqb[tid][2] = a.z; sm.g.fqb[tid][3] = a.w;
      sm.g.fqb[tid][4] = c4.x; sm.g.fqb[tid][5] = c4.y; sm.g.fqb[tid][6] = c4.z; sm.g.fqb[tid][7] = c4.w;
    }
    __syncthreads();
    int o8 = tid >> 4;
    int obase = o8 << 3;
    float fq[8];
#pragma unroll
    for (int c = 0; c < 8; c++) fq[c] = sm.g.fqb[nl][c];
    float tv[8], Ar[64];
#pragma unroll
    for (int oo = 0; oo < 8; oo++) {
      float acc = 0.f;
#pragma unroll
      for (int c = 0; c < 8; c++) acc += sm.g.Dlds[obase + oo][c] * fq[c];
      tv[oo] = acc;
#pragma unroll
      for (int c = 0; c < 8; c++) Ar[oo * 8 + c] = sm.g.Alds[obase + oo][c];
    }
    float mx[8], mn[8];
#pragma unroll
    for (int oo = 0; oo < 8; oo++) { mx[oo] = -3.4e38f; mn[oo] = 3.4e38f; }
    for (int k = 0; k < 16; k++) {
      float4 g0 = *(const float4*)&sm.g.fnb[nl][k * 8];
      float4 g1 = *(const float4*)&sm.g.fnb[nl][k * 8 + 4];
      float fn[8] = {g0.x, g0.y, g0.z, g0.w, g1.x, g1.y, g1.z, g1.w};
#pragma unroll
      for (int oo = 0; oo < 8; oo++) {
        float acc = tv[oo];
#pragma unroll
        for (int c = 0; c < 8; c++) acc += Ar[oo * 8 + c] * fn[c];
        mx[oo] = fmaxf(mx[oo], acc);
        mn[oo] = fminf(mn[oo], acc);
      }
    }
    int g = o8 >> 2;
    int j = j0 + nl;
    float mu = musd[((b << 2) + g) * 2];
    float rstd = musd[((b << 2) + g) * 2 + 1];
#pragma unroll
    for (int oo = 0; oo < 8; oo++) {
      int o = obase + oo;
      float w = gnw[o];
      float v = (w >= 0.f) ? mx[oo] : mn[oo];   // leaky∘affine weakly monotone
      float y = (v - mu) * rstd * w + gnb[o];
      y = (y >= 0.f) ? y : 0.2f * y;
      out1[(((size_t)b * 128 + o) << 10) + j] = y;
    }
  } else {
    // ================= gather: coor + fps_idx as float ======================
    if (tid == 0) spin_ge(&ctl->fps_done, 8);
    __syncthreads();
    __threadfence();
    int t = (bk - 2824) * 256 + tid;              // 8192 = B*NPT
    int b = t >> 10, j = t & 1023;
    int i = fps_g[t];
    const float* xb = x + (size_t)b * 3 * NQ;
    out[((size_t)b * 3 + 0) * NPT + j] = xb[i];
    out[((size_t)b * 3 + 1) * NPT + j] = xb[NQ + i];
    out[((size_t)b * 3 + 2) * NPT + j] = xb[2 * NQ + i];
    out[24576 + 1048576 + t] = (float)i;
  }
}

extern "C" void kernel_launch(void* const* d_in, const int* in_sizes, int n_in,
                              void* d_out, int out_size, void* d_ws, size_t ws_size,
                              hipStream_t stream) {
  const float* x    = (const float*)d_in[0];
  const float* f    = (const float*)d_in[1];
  const float* w_in = (const float*)d_in[2];
  const float* b_in = (const float*)d_in[3];
  const float* w1   = (const float*)d_in[4];
  const float* gnw  = (const float*)d_in[5];
  const float* gnb  = (const float*)d_in[6];
  float* out = (float*)d_out;

  char* ws = (char*)d_ws;
  float*  f8t   = (float*)(ws);                               // 1 MB
  int*    knn   = (int*)(ws + (1 << 20));                     // 2 MB
  int*    fps   = (int*)(ws + (3 << 20));                     // 32 KB
  double* stats = (double*)(ws + (3 << 20) + 32768);          // 512 B
  Ctl*    ctl   = (Ctl*)(ws + (3 << 20) + 32768 + 512);       // 64 B
  float*  musd  = (float*)(ws + (3 << 20) + 32768 + 512 + 64);// 256 B

  hipMemsetAsync(stats, 0, 512 + 64, stream);                 // stats + ctl
  mega_kernel<<<2856, 256, 0, stream>>>(x, f, w_in, b_in, w1, gnw, gnb,
                                        f8t, knn, fps, stats, musd, ctl, out);
}